// Round 4
// baseline (254.813 us; speedup 1.0000x reference)
//
#include <hip/hip_runtime.h>
#include <stdint.h>
#include <math.h>

#define NB 16
#define NP 6000
#define NG 128
#define NC 10
#define CHUNK 24     // ceil(NP/256)
#define SELMAX 8     // dyn <= 4 for head_idx=5; slack for safety
#define GSTR 24      // padded per-GT stride
#define GCOLS 2      // columns per fused block (same b)

static_assert(CHUNK * 256 >= NP, "chunk covers P");

typedef unsigned long long u64;
#define NBPs ((size_t)NB * NP)

__device__ __forceinline__ uint32_t fkey(float f) {
  uint32_t u = __float_as_uint(f);
  return (u & 0x80000000u) ? ~u : (u | 0x80000000u);
}
__device__ __forceinline__ float fkey_inv(uint32_t k) {
  uint32_t u = (k & 0x80000000u) ? (k & 0x7fffffffu) : ~k;
  return __uint_as_float(u);
}
__device__ __forceinline__ u64 shfl_xor_u64(u64 v, int m) {
  uint32_t lo = (uint32_t)v, hi = (uint32_t)(v >> 32);
  lo = (uint32_t)__shfl_xor((int)lo, m, 64);
  hi = (uint32_t)__shfl_xor((int)hi, m, 64);
  return ((u64)hi << 32) | lo;
}

// ---------------------------------------------------------------------------
// Per-GT derived quantities, GSTR floats per (b,g):
// [0:3) gmin, [3:6) gmax, [6:9) ctr lo, [9:12) ctr hi, [12:20) gt_norm,
// [20] vg, [21] label bits.
__global__ void prep_gt_kernel(const float* __restrict__ gt_boxes,
                               const int* __restrict__ gt_labels,
                               float* __restrict__ gtaux) {
#pragma clang fp contract(off)
  int b = blockIdx.x, g = threadIdx.x;
  if (g >= NG) return;
  const float* gb = gt_boxes + ((size_t)b * NG + g) * 7;
  float cx = gb[0], cy = gb[1], cz = gb[2];
  float dx = gb[3], dy = gb[4], dz = gb[5];
  float yaw = gb[6];
  float cyw = cosf(yaw), syw = sinf(yaw);
  float ca = fabsf(cyw), sa = fabsf(syw);
  float hx = 0.5f * (dx * ca + dy * sa);
  float hy = 0.5f * (dx * sa + dy * ca);
  float hz = 0.5f * dz;
  float gmin0 = cx - hx, gmin1 = cy - hy, gmin2 = cz - hz;
  float gmax0 = cx + hx, gmax1 = cy + hy, gmax2 = cz + hz;
  float vg = ((gmax0 - gmin0) * (gmax1 - gmin1)) * (gmax2 - gmin2);
  float* o = gtaux + ((size_t)b * NG + g) * GSTR;
  o[0] = gmin0; o[1] = gmin1; o[2] = gmin2;
  o[3] = gmax0; o[4] = gmax1; o[5] = gmax2;
  o[6] = cx - 1.5f * dx; o[7] = cy - 1.5f * dy; o[8] = cz - 1.5f * dz;
  o[9] = cx + 1.5f * dx; o[10] = cy + 1.5f * dy; o[11] = cz + 1.5f * dz;
  o[12] = cx; o[13] = cy; o[14] = cz;
  o[15] = logf(dx); o[16] = logf(dy); o[17] = logf(dz);
  o[18] = syw; o[19] = cyw;
  o[20] = vg;
  o[21] = __int_as_float(gt_labels[(size_t)b * NG + g]);
  o[22] = 0.0f; o[23] = 0.0f;
}

// ---------------------------------------------------------------------------
// Per-pred compaction: focal table -> clst planes, box decode + valid/pen ->
// paux AoS [idx][16]: 0..7 = b0..b7, 8..10 = pmin, 11..13 = pmax, 14 = vp,
// 15 = pen (0 or 10000).  Also inits rowcnt/rowassign.
__global__ __launch_bounds__(256) void prep_pred_kernel(
    const float* __restrict__ pred_logits,
    const float* __restrict__ pred_boxes,
    const float* __restrict__ gtaux,
    float* __restrict__ paux,
    float* __restrict__ clst,
    int* __restrict__ rowcnt,
    int* __restrict__ rowassign) {
#pragma clang fp contract(off)
  __shared__ float shg[NG * 12];
  const int b = blockIdx.y, tid = threadIdx.x;
  for (int j = tid; j < NG * 12; j += 256) {
    int g = j / 12, k = j % 12;
    shg[j] = gtaux[((size_t)b * NG + g) * GSTR + k];
  }
  __syncthreads();
  const int p = blockIdx.x * 256 + tid;
  if (p >= NP) return;
  const size_t idx = (size_t)b * NP + p;
  const float* lg = pred_logits + idx * NC;
  for (int c = 0; c < NC; ++c) {
    float x = lg[c];
    float pr = 1.0f / (1.0f + expf(-x));
    float neg = (-logf(1.0f - pr + 1e-12f) * 0.75f) * (pr * pr);
    float pos = (-logf(pr + 1e-12f) * 0.25f) * ((1.0f - pr) * (1.0f - pr));
    clst[(size_t)c * NBPs + idx] = (pos - neg) * 2.0f;
  }
  const float* bx = pred_boxes + idx * 10;
  float b0 = bx[0], b1 = bx[1], b2 = bx[2], b3 = bx[3], b4 = bx[4];
  float b5 = bx[5], b6 = bx[6], b7 = bx[7];
  float yaw = atan2f(b6, b7);
  float d0 = expf(b3), d1 = expf(b4), d2 = expf(b5);
  float ca = fabsf(cosf(yaw)), sa = fabsf(sinf(yaw));
  float hx = 0.5f * (d0 * ca + d1 * sa);
  float hy = 0.5f * (d0 * sa + d1 * ca);
  float hz = 0.5f * d2;
  float pmin0 = b0 - hx, pmin1 = b1 - hy, pmin2 = b2 - hz;
  float pmax0 = b0 + hx, pmax1 = b1 + hy, pmax2 = b2 + hz;
  float vp = ((pmax0 - pmin0) * (pmax1 - pmin1)) * (pmax2 - pmin2);
  int valid = 0;
  for (int g = 0; g < NG; ++g) {
    const float* s = &shg[g * 12];
    bool inb = (b0 > s[0]) && (b0 < s[3]) && (b1 > s[1]) && (b1 < s[4]) &&
               (b2 > s[2]) && (b2 < s[5]);
    bool inc = (b0 > s[6]) && (b0 < s[9]) && (b1 > s[7]) && (b1 < s[10]) &&
               (b2 > s[8]) && (b2 < s[11]);
    if (inb || inc) { valid = 1; break; }
  }
  float* o = paux + idx * 16;
  o[0] = b0; o[1] = b1; o[2] = b2; o[3] = b3;
  o[4] = b4; o[5] = b5; o[6] = b6; o[7] = b7;
  o[8] = pmin0; o[9] = pmin1; o[10] = pmin2;
  o[11] = pmax0; o[12] = pmax1; o[13] = pmax2;
  o[14] = vp; o[15] = valid ? 0.0f : 10000.0f;
  rowcnt[idx] = 0;
  rowassign[idx] = 0x7fffffff;
}

// Per-column GT parameters (wave-uniform scalars).
struct GTp {
  float gmin0, gmin1, gmin2, gmax0, gmax1, gmax2;
  float lo0, lo1, lo2, hi0, hi1, hi2;
  float gtn0, gtn1, gtn2, gtn3, gtn4, gtn5, gtn6, gtn7;
  float vg;
  int label;
};
__device__ __forceinline__ GTp load_gt(const float* __restrict__ gtaux,
                                       int b, int g) {
  const float* ga = gtaux + ((size_t)b * NG + g) * GSTR;
  GTp t;
  t.gmin0 = ga[0]; t.gmin1 = ga[1]; t.gmin2 = ga[2];
  t.gmax0 = ga[3]; t.gmax1 = ga[4]; t.gmax2 = ga[5];
  t.lo0 = ga[6]; t.lo1 = ga[7]; t.lo2 = ga[8];
  t.hi0 = ga[9]; t.hi1 = ga[10]; t.hi2 = ga[11];
  t.gtn0 = ga[12]; t.gtn1 = ga[13]; t.gtn2 = ga[14]; t.gtn3 = ga[15];
  t.gtn4 = ga[16]; t.gtn5 = ga[17]; t.gtn6 = ga[18]; t.gtn7 = ga[19];
  t.vg = ga[20];
  t.label = __float_as_int(ga[21]);
  return t;
}

// Exact R2 cost arithmetic (order preserved; caller adds pen last).
__device__ __forceinline__ float cost_base(
    float b0, float b1, float b2, float b3, float b4, float b5, float b6,
    float b7, float pmin0, float pmin1, float pmin2, float pmax0, float pmax1,
    float pmax2, float vp, float cls, const GTp& t, float* iou_out) {
#pragma clang fp contract(off)
  float r = fabsf(b0 - t.gtn0);
  r = r + fabsf(b1 - t.gtn1);
  r = r + fabsf(b2 - t.gtn2);
  r = r + fabsf(b3 - t.gtn3);
  r = r + fabsf(b4 - t.gtn4);
  r = r + fabsf(b5 - t.gtn5);
  r = r + fabsf(b6 - t.gtn6);
  r = r + fabsf(b7 - t.gtn7);
  float reg = r * 0.25f;
  float li0 = fmaxf(pmin0, t.gmin0), li1 = fmaxf(pmin1, t.gmin1),
        li2 = fmaxf(pmin2, t.gmin2);
  float hj0 = fminf(pmax0, t.gmax0), hj1 = fminf(pmax1, t.gmax1),
        hj2 = fminf(pmax2, t.gmax2);
  float e0 = fmaxf(hj0 - li0, 0.0f), e1 = fmaxf(hj1 - li1, 0.0f),
        e2 = fmaxf(hj2 - li2, 0.0f);
  float inter = (e0 * e1) * e2;
  float iou = inter / (((vp + t.vg) - inter) + 1e-7f);
  bool inb = (b0 > t.gmin0) && (b0 < t.gmax0) && (b1 > t.gmin1) &&
             (b1 < t.gmax1) && (b2 > t.gmin2) && (b2 < t.gmax2);
  bool inc = (b0 > t.lo0) && (b0 < t.hi0) && (b1 > t.lo1) && (b1 < t.hi1) &&
             (b2 > t.lo2) && (b2 < t.hi2);
  *iou_out = iou;
  return ((cls + reg) + (-(iou * 0.25f))) + ((inb && inc) ? 0.0f : 100.0f);
}

// ---------------------------------------------------------------------------
// Fused per-column selection, GCOLS columns (same b) per block, no matrices.
// Streaming top-5 iou (values) + register-resident costs; dyn argmin rounds
// with register sel[] exclusion.  XCD-aware mapping: blocks on XCD x handle
// only b in {2x, 2x+1} -> per-XCD L2 working set ~1.3 MB.
__global__ __launch_bounds__(256) void fused_select_kernel(
    const float* __restrict__ paux,
    const float* __restrict__ clst,
    const float* __restrict__ gtaux,
    const int* __restrict__ head_ptr,
    int* __restrict__ colsel,
    int* __restrict__ rowcnt,
    int* __restrict__ rowassign) {
#pragma clang fp contract(off)
  const int f = blockIdx.x;           // 0..1023
  const int xcd = f & 7;
  const int j = f >> 3;               // 0..127
  const int b = xcd * 2 + (j & 1);    // 0..15
  const int g0 = (j >> 1) * 2;        // 0,2,..,126
  const int tid = threadIdx.x, lane = tid & 63, wid = tid >> 6;

  GTp gt[GCOLS];
#pragma unroll
  for (int c = 0; c < GCOLS; ++c) gt[c] = load_gt(gtaux, b, g0 + c);

  const size_t rowbase = (size_t)b * NP;
  float lc[GCOLS][CHUNK];
  float t5[GCOLS][5];
#pragma unroll
  for (int c = 0; c < GCOLS; ++c)
#pragma unroll
    for (int q = 0; q < 5; ++q) t5[c][q] = -INFINITY;

#pragma unroll
  for (int i = 0; i < CHUNK; ++i) {
    const int p = i * 256 + tid;
    if (p < NP) {
      const size_t idx = rowbase + p;
      const float4* pa = (const float4*)(paux + idx * 16);
      float4 A = pa[0], Bq = pa[1], Cq = pa[2], Dq = pa[3];
      const float pen = Dq.w;
#pragma unroll
      for (int c = 0; c < GCOLS; ++c) {
        float cls = clst[(size_t)gt[c].label * NBPs + idx];
        float iou;
        float cc = cost_base(A.x, A.y, A.z, A.w, Bq.x, Bq.y, Bq.z, Bq.w,
                             Cq.x, Cq.y, Cq.z, Cq.w, Dq.x, Dq.y, Dq.z,
                             cls, gt[c], &iou);
        lc[c][i] = cc + pen;
        if (iou > t5[c][4]) {
          t5[c][4] = iou;
#pragma unroll
          for (int q = 4; q > 0; --q) {
            if (t5[c][q] > t5[c][q - 1]) {
              float tmp = t5[c][q]; t5[c][q] = t5[c][q - 1]; t5[c][q - 1] = tmp;
            }
          }
        }
      }
    } else {
#pragma unroll
      for (int c = 0; c < GCOLS; ++c) lc[c][i] = INFINITY;
    }
  }

  __shared__ u64 sred[4];
  const int hd = head_ptr[0];
  int sel[GCOLS][SELMAX];
  int dynv[GCOLS];

#pragma unroll
  for (int c = 0; c < GCOLS; ++c) {
    // --- block top-5 iou via 5-round k-way merge of per-thread sorted lists
    int hp = 0;
    float sum5 = 0.0f;
    for (int rround = 0; rround < 5; ++rround) {
      float cand = -INFINITY;
#pragma unroll
      for (int q = 0; q < 5; ++q)
        if (hp == q) cand = t5[c][q];
      u64 key = ((u64)fkey(cand) << 32) | (unsigned)tid;
#pragma unroll
      for (int o = 1; o < 64; o <<= 1) {
        u64 t = shfl_xor_u64(key, o);
        if (t > key) key = t;
      }
      __syncthreads();
      if (lane == 0) sred[wid] = key;
      __syncthreads();
      u64 rr = sred[0];
      if (sred[1] > rr) rr = sred[1];
      if (sred[2] > rr) rr = sred[2];
      if (sred[3] > rr) rr = sred[3];
      float v = fkey_inv((uint32_t)(rr >> 32));
      sum5 = (rround == 0) ? v : (sum5 + v);   // descending-order left-assoc
      if (tid == (int)(rr & 0xffffffffu)) hp++;
    }
    float adj = sum5 - 0.5f * (float)(6 - hd);
    int dyn = (int)adj;               // trunc toward zero == astype(int32)
    if (dyn < 1) dyn = 1;
    if (dyn > SELMAX) dyn = SELMAX;
    dynv[c] = dyn;

    // --- dyn rounds of block argmin with register-sel exclusion
    for (int k = 0; k < dyn; ++k) {
      u64 best = ~0ull;
#pragma unroll
      for (int i = 0; i < CHUNK; ++i) {
        const int p = i * 256 + tid;
        bool ok = true;
#pragma unroll
        for (int q = 0; q < SELMAX; ++q) ok = ok && (q >= k || p != sel[c][q]);
        if (ok) {
          u64 key = ((u64)fkey(lc[c][i]) << 32) | (unsigned)p;
          if (key < best) best = key;
        }
      }
#pragma unroll
      for (int o = 1; o < 64; o <<= 1) {
        u64 t = shfl_xor_u64(best, o);
        if (t < best) best = t;
      }
      __syncthreads();
      if (lane == 0) sred[wid] = best;
      __syncthreads();
      u64 rr = sred[0];
      if (sred[1] < rr) rr = sred[1];
      if (sred[2] < rr) rr = sred[2];
      if (sred[3] < rr) rr = sred[3];
      int pw = (int)(rr & 0xffffffffu);
#pragma unroll
      for (int q = 0; q < SELMAX; ++q)
        if (q == k) sel[c][q] = pw;
    }
  }

  if (tid == 0) {
#pragma unroll
    for (int c = 0; c < GCOLS; ++c) {
      const size_t cb = ((size_t)(b * NG + g0 + c)) * SELMAX;
      for (int q = 0; q < SELMAX; ++q) {
        int s = (q < dynv[c]) ? sel[c][q] : -1;
        colsel[cb + q] = s;
        if (s >= 0) {
          atomicAdd(&rowcnt[rowbase + s], 1);
          atomicMin(&rowassign[rowbase + s], g0 + c);
        }
      }
    }
  }
}

// Column counts part (a): selected rows that stayed (rowcnt==1).
__global__ void colcnt_a_kernel(const int* __restrict__ colsel,
                                const int* __restrict__ rowcnt,
                                int* __restrict__ colcnt) {
  int i = blockIdx.x * 256 + threadIdx.x;
  if (i >= NB * NG) return;
  int b = i / NG;
  int cnt = 0;
  for (int k = 0; k < SELMAX; ++k) {
    int s = colsel[(size_t)i * SELMAX + k];
    if (s >= 0 && rowcnt[(size_t)b * NP + s] == 1) cnt++;
  }
  colcnt[i] = cnt;
}

// Prior rows (rowcnt>1): recompute their 128 costs, argmin -> rowmin, and
// scatter into colcnt (part b).  Rare rows; most threads exit immediately.
__global__ __launch_bounds__(256) void rowmin_prior_kernel(
    const float* __restrict__ paux,
    const float* __restrict__ clst,
    const float* __restrict__ gtaux,
    const int* __restrict__ rowcnt,
    int* __restrict__ rowminArr,
    int* __restrict__ colcnt) {
#pragma clang fp contract(off)
  const int b = blockIdx.y, p = blockIdx.x * 256 + threadIdx.x;
  if (p >= NP) return;
  const size_t idx = (size_t)b * NP + p;
  if (rowcnt[idx] <= 1) return;
  const float4* pa = (const float4*)(paux + idx * 16);
  float4 A = pa[0], Bq = pa[1], Cq = pa[2], Dq = pa[3];
  const float pen = Dq.w;
  float best = INFINITY;
  int bg = 0;
  for (int g = 0; g < NG; ++g) {
    GTp t = load_gt(gtaux, b, g);
    float cls = clst[(size_t)t.label * NBPs + idx];
    float iou;
    float cc = cost_base(A.x, A.y, A.z, A.w, Bq.x, Bq.y, Bq.z, Bq.w,
                         Cq.x, Cq.y, Cq.z, Cq.w, Dq.x, Dq.y, Dq.z,
                         cls, t, &iou);
    float cv = cc + pen;
    if (cv < best) { best = cv; bg = g; }   // strict <: first-g tiebreak
  }
  rowminArr[idx] = bg;
  atomicAdd(&colcnt[b * NG + bg], 1);
}

// Empty columns: recompute the column's costs over never-matched rows, argmin.
__global__ __launch_bounds__(256) void fixup_kernel(
    const float* __restrict__ paux,
    const float* __restrict__ clst,
    const float* __restrict__ gtaux,
    const int* __restrict__ colcnt,
    const int* __restrict__ rowcnt,
    int* __restrict__ rowassign) {
#pragma clang fp contract(off)
  const int g = blockIdx.x, b = blockIdx.y, tid = threadIdx.x;
  if (colcnt[b * NG + g] != 0) return;  // uniform across block
  const size_t rowbase = (size_t)b * NP;
  GTp t = load_gt(gtaux, b, g);
  u64 best = ~0ull;
  for (int p = tid; p < NP; p += 256) {
    const size_t idx = rowbase + p;
    if (rowcnt[idx] == 0) {
      const float4* pa = (const float4*)(paux + idx * 16);
      float4 A = pa[0], Bq = pa[1], Cq = pa[2], Dq = pa[3];
      float cls = clst[(size_t)t.label * NBPs + idx];
      float iou;
      float cc = cost_base(A.x, A.y, A.z, A.w, Bq.x, Bq.y, Bq.z, Bq.w,
                           Cq.x, Cq.y, Cq.z, Cq.w, Dq.x, Dq.y, Dq.z,
                           cls, t, &iou);
      u64 key = ((u64)fkey(cc + Dq.w) << 32) | (unsigned)p;
      if (key < best) best = key;
    }
  }
  __shared__ u64 red[256];
  red[tid] = best;
  __syncthreads();
  for (int offr = 128; offr > 0; offr >>= 1) {
    if (tid < offr) { if (red[tid + offr] < red[tid]) red[tid] = red[tid + offr]; }
    __syncthreads();
  }
  if (tid == 0) {
    int pos = (int)(red[0] & 0xffffffffu);
    atomicMin(&rowassign[rowbase + pos], g);  // min g == argmax first-1
  }
}

__global__ void output_kernel(const int* __restrict__ rowcnt,
                              const int* __restrict__ rowassign,
                              const int* __restrict__ rowminArr,
                              int* __restrict__ out) {
  int b = blockIdx.y, p = blockIdx.x * 256 + threadIdx.x;
  if (p >= NP) return;
  size_t idx = (size_t)b * NP + p;
  int rc = rowcnt[idx];
  int fg, m;
  if (rc == 0) {
    int ra = rowassign[idx];
    if (ra == 0x7fffffff) { fg = 0; m = -1; }
    else { fg = 1; m = ra; }          // fixup-assigned (min g)
  } else if (rc == 1) {
    fg = 1; m = rowassign[idx];       // single selecting column
  } else {
    fg = 1; m = rowminArr[idx];       // prior row -> one-hot at row argmin
  }
  out[idx] = fg;
  out[(size_t)NB * NP + idx] = m;
}

// ---------------------------------------------------------------------------
extern "C" void kernel_launch(void* const* d_in, const int* in_sizes, int n_in,
                              void* d_out, int out_size, void* d_ws, size_t ws_size,
                              hipStream_t stream) {
  const float* pred_logits = (const float*)d_in[0];
  const float* pred_boxes = (const float*)d_in[1];
  const float* gt_boxes = (const float*)d_in[2];
  const int* gt_labels = (const int*)d_in[3];
  const int* head = (const int*)d_in[4];
  (void)in_sizes; (void)n_in; (void)out_size; (void)ws_size;

  char* w = (char*)d_ws;
  size_t off = 0;
  auto alloc = [&](size_t bytes) -> void* {
    void* p = w + off;
    off += (bytes + 255) & ~(size_t)255;
    return p;
  };
  float* paux = (float*)alloc((size_t)NB * NP * 16 * 4);   // 6.1 MB AoS
  float* clst = (float*)alloc((size_t)NC * NB * NP * 4);   // 3.8 MB planes
  float* gtaux = (float*)alloc((size_t)NB * NG * GSTR * 4);
  int* colsel = (int*)alloc((size_t)NB * NG * SELMAX * 4);
  int* rowcnt = (int*)alloc((size_t)NB * NP * 4);
  int* rowassign = (int*)alloc((size_t)NB * NP * 4);
  int* rowminArr = (int*)alloc((size_t)NB * NP * 4);
  int* colcnt = (int*)alloc((size_t)NB * NG * 4);

  int* out = (int*)d_out;
  dim3 blk(256);
  prep_gt_kernel<<<dim3(NB), dim3(128), 0, stream>>>(gt_boxes, gt_labels, gtaux);
  prep_pred_kernel<<<dim3((NP + 255) / 256, NB), blk, 0, stream>>>(
      pred_logits, pred_boxes, gtaux, paux, clst, rowcnt, rowassign);
  fused_select_kernel<<<dim3(NB * NG / GCOLS), blk, 0, stream>>>(
      paux, clst, gtaux, head, colsel, rowcnt, rowassign);
  colcnt_a_kernel<<<dim3((NB * NG + 255) / 256), blk, 0, stream>>>(colsel, rowcnt, colcnt);
  rowmin_prior_kernel<<<dim3((NP + 255) / 256, NB), blk, 0, stream>>>(
      paux, clst, gtaux, rowcnt, rowminArr, colcnt);
  fixup_kernel<<<dim3(NG, NB), blk, 0, stream>>>(
      paux, clst, gtaux, colcnt, rowcnt, rowassign);
  output_kernel<<<dim3((NP + 255) / 256, NB), blk, 0, stream>>>(
      rowcnt, rowassign, rowminArr, out);
}

// Round 5
// 110.351 us; speedup vs baseline: 2.3091x; 2.3091x over previous
//
#include <hip/hip_runtime.h>
#include <stdint.h>
#include <math.h>

#define NB 16
#define NP 6000
#define NG 128
#define NC 10
#define SELMAX 8     // dyn <= 4 for head_idx=5; slack for safety
#define GSTR 24      // padded per-GT stride
#define GCH 32       // g's per costmat block (NG/4)
#define VCHUNK 6     // select: 6 float4-steps * 1024 >= NP

typedef unsigned long long u64;
#define NBPs ((size_t)NB * NP)

__device__ __forceinline__ uint32_t fkey(float f) {
  // monotone float->uint mapping for lexicographic ordering
  uint32_t u = __float_as_uint(f);
  return (u & 0x80000000u) ? ~u : (u | 0x80000000u);
}
__device__ __forceinline__ float fkey_inv(uint32_t k) {
  uint32_t u = (k & 0x80000000u) ? (k & 0x7fffffffu) : ~k;
  return __uint_as_float(u);
}
__device__ __forceinline__ u64 shfl_xor_u64(u64 v, int m) {
  uint32_t lo = (uint32_t)v, hi = (uint32_t)(v >> 32);
  lo = (uint32_t)__shfl_xor((int)lo, m, 64);
  hi = (uint32_t)__shfl_xor((int)hi, m, 64);
  return ((u64)hi << 32) | lo;
}
// block reduce over 256 threads (4 waves); sred is 4-entry LDS.
__device__ __forceinline__ u64 block_min_u64(u64 v, u64* sred, int lane, int wid) {
#pragma unroll
  for (int o = 1; o < 64; o <<= 1) {
    u64 t = shfl_xor_u64(v, o);
    if (t < v) v = t;
  }
  __syncthreads();            // protect sred from previous round's readers
  if (lane == 0) sred[wid] = v;
  __syncthreads();
  u64 r = sred[0];
  if (sred[1] < r) r = sred[1];
  if (sred[2] < r) r = sred[2];
  if (sred[3] < r) r = sred[3];
  return r;
}
__device__ __forceinline__ u64 block_max_u64(u64 v, u64* sred, int lane, int wid) {
#pragma unroll
  for (int o = 1; o < 64; o <<= 1) {
    u64 t = shfl_xor_u64(v, o);
    if (t > v) v = t;
  }
  __syncthreads();
  if (lane == 0) sred[wid] = v;
  __syncthreads();
  u64 r = sred[0];
  if (sred[1] > r) r = sred[1];
  if (sred[2] > r) r = sred[2];
  if (sred[3] > r) r = sred[3];
  return r;
}

// ---------------------------------------------------------------------------
// Per-GT derived quantities, GSTR floats per (b,g).
__global__ void prep_gt_kernel(const float* __restrict__ gt_boxes,
                               const int* __restrict__ gt_labels,
                               float* __restrict__ gtaux) {
#pragma clang fp contract(off)
  int b = blockIdx.x, g = threadIdx.x;
  if (g >= NG) return;
  const float* gb = gt_boxes + ((size_t)b * NG + g) * 7;
  float cx = gb[0], cy = gb[1], cz = gb[2];
  float dx = gb[3], dy = gb[4], dz = gb[5];
  float yaw = gb[6];
  float cyw = cosf(yaw), syw = sinf(yaw);
  float ca = fabsf(cyw), sa = fabsf(syw);
  float hx = 0.5f * (dx * ca + dy * sa);
  float hy = 0.5f * (dx * sa + dy * ca);
  float hz = 0.5f * dz;
  float gmin0 = cx - hx, gmin1 = cy - hy, gmin2 = cz - hz;
  float gmax0 = cx + hx, gmax1 = cy + hy, gmax2 = cz + hz;
  float vg = ((gmax0 - gmin0) * (gmax1 - gmin1)) * (gmax2 - gmin2);
  float* o = gtaux + ((size_t)b * NG + g) * GSTR;
  o[0] = gmin0; o[1] = gmin1; o[2] = gmin2;
  o[3] = gmax0; o[4] = gmax1; o[5] = gmax2;
  o[6] = cx - 1.5f * dx; o[7] = cy - 1.5f * dy; o[8] = cz - 1.5f * dz;
  o[9] = cx + 1.5f * dx; o[10] = cy + 1.5f * dy; o[11] = cz + 1.5f * dz;
  o[12] = cx; o[13] = cy; o[14] = cz;
  o[15] = logf(dx); o[16] = logf(dy); o[17] = logf(dz);
  o[18] = syw; o[19] = cyw;
  o[20] = vg;
  o[21] = __int_as_float(gt_labels[(size_t)b * NG + g]);
  o[22] = 0.0f; o[23] = 0.0f;
}

// ---------------------------------------------------------------------------
// Per-pred streaming: focal table -> clst planes, box decode -> paux AoS[16].
// Also zero-inits rowcnt/rowassign/validArr.  NO per-gt loop here.
__global__ __launch_bounds__(256) void prep_pred_kernel(
    const float* __restrict__ pred_logits,
    const float* __restrict__ pred_boxes,
    float* __restrict__ paux,
    float* __restrict__ clst,
    int* __restrict__ validArr,
    int* __restrict__ rowcnt,
    int* __restrict__ rowassign) {
#pragma clang fp contract(off)
  const int b = blockIdx.y, tid = threadIdx.x;
  const int p = blockIdx.x * 256 + tid;
  if (p >= NP) return;
  const size_t idx = (size_t)b * NP + p;
  const float* lg = pred_logits + idx * NC;
  for (int c = 0; c < NC; ++c) {
    float x = lg[c];
    float pr = 1.0f / (1.0f + expf(-x));
    float neg = (-logf(1.0f - pr + 1e-12f) * 0.75f) * (pr * pr);
    float pos = (-logf(pr + 1e-12f) * 0.25f) * ((1.0f - pr) * (1.0f - pr));
    clst[(size_t)c * NBPs + idx] = (pos - neg) * 2.0f;
  }
  const float* bx = pred_boxes + idx * 10;
  float b0 = bx[0], b1 = bx[1], b2 = bx[2], b3 = bx[3], b4 = bx[4];
  float b5 = bx[5], b6 = bx[6], b7 = bx[7];
  float yaw = atan2f(b6, b7);
  float d0 = expf(b3), d1 = expf(b4), d2 = expf(b5);
  float ca = fabsf(cosf(yaw)), sa = fabsf(sinf(yaw));
  float hx = 0.5f * (d0 * ca + d1 * sa);
  float hy = 0.5f * (d0 * sa + d1 * ca);
  float hz = 0.5f * d2;
  float* o = paux + idx * 16;
  o[0] = b0; o[1] = b1; o[2] = b2; o[3] = b3;
  o[4] = b4; o[5] = b5; o[6] = b6; o[7] = b7;
  o[8] = b0 - hx; o[9] = b1 - hy; o[10] = b2 - hz;
  o[11] = b0 + hx; o[12] = b1 + hy; o[13] = b2 + hz;
  float pmin0 = o[8], pmin1 = o[9], pmin2 = o[10];
  float pmax0 = o[11], pmax1 = o[12], pmax2 = o[13];
  o[14] = ((pmax0 - pmin0) * (pmax1 - pmin1)) * (pmax2 - pmin2);
  o[15] = 0.0f;
  validArr[idx] = 0;
  rowcnt[idx] = 0;
  rowassign[idx] = 0x7fffffff;
}

// Per-column GT parameters (block-uniform -> scalar loads).
struct GTp {
  float gmin0, gmin1, gmin2, gmax0, gmax1, gmax2;
  float lo0, lo1, lo2, hi0, hi1, hi2;
  float gtn0, gtn1, gtn2, gtn3, gtn4, gtn5, gtn6, gtn7;
  float vg;
  int label;
};
__device__ __forceinline__ GTp load_gt(const float* __restrict__ gtaux,
                                       int b, int g) {
  const float* ga = gtaux + ((size_t)b * NG + g) * GSTR;
  GTp t;
  t.gmin0 = ga[0]; t.gmin1 = ga[1]; t.gmin2 = ga[2];
  t.gmax0 = ga[3]; t.gmax1 = ga[4]; t.gmax2 = ga[5];
  t.lo0 = ga[6]; t.lo1 = ga[7]; t.lo2 = ga[8];
  t.hi0 = ga[9]; t.hi1 = ga[10]; t.hi2 = ga[11];
  t.gtn0 = ga[12]; t.gtn1 = ga[13]; t.gtn2 = ga[14]; t.gtn3 = ga[15];
  t.gtn4 = ga[16]; t.gtn5 = ga[17]; t.gtn6 = ga[18]; t.gtn7 = ga[19];
  t.vg = ga[20];
  t.label = __float_as_int(ga[21]);
  return t;
}

// Exact reference arithmetic; pen (row-valid) is NOT included (consumers add).
__device__ __forceinline__ float cost_base(
    float b0, float b1, float b2, float b3, float b4, float b5, float b6,
    float b7, float pmin0, float pmin1, float pmin2, float pmax0, float pmax1,
    float pmax2, float vp, float cls, const GTp& t, float* iou_out,
    int* valid_out) {
#pragma clang fp contract(off)
  float r = fabsf(b0 - t.gtn0);
  r = r + fabsf(b1 - t.gtn1);
  r = r + fabsf(b2 - t.gtn2);
  r = r + fabsf(b3 - t.gtn3);
  r = r + fabsf(b4 - t.gtn4);
  r = r + fabsf(b5 - t.gtn5);
  r = r + fabsf(b6 - t.gtn6);
  r = r + fabsf(b7 - t.gtn7);
  float reg = r * 0.25f;
  float li0 = fmaxf(pmin0, t.gmin0), li1 = fmaxf(pmin1, t.gmin1),
        li2 = fmaxf(pmin2, t.gmin2);
  float hj0 = fminf(pmax0, t.gmax0), hj1 = fminf(pmax1, t.gmax1),
        hj2 = fminf(pmax2, t.gmax2);
  float e0 = fmaxf(hj0 - li0, 0.0f), e1 = fmaxf(hj1 - li1, 0.0f),
        e2 = fmaxf(hj2 - li2, 0.0f);
  float inter = (e0 * e1) * e2;
  float iou = inter / (((vp + t.vg) - inter) + 1e-7f);
  bool inb = (b0 > t.gmin0) && (b0 < t.gmax0) && (b1 > t.gmin1) &&
             (b1 < t.gmax1) && (b2 > t.gmin2) && (b2 < t.gmax2);
  bool inc = (b0 > t.lo0) && (b0 < t.hi0) && (b1 > t.lo1) && (b1 < t.hi1) &&
             (b2 > t.lo2) && (b2 < t.hi2);
  *iou_out = iou;
  *valid_out = (inb || inc) ? 1 : 0;
  return ((cls + reg) + (-(iou * 0.25f))) + ((inb && inc) ? 0.0f : 100.0f);
}

// ---------------------------------------------------------------------------
// Cost/IoU matrices, g-split 4-ways for occupancy.  Pred-per-thread; GT via
// uniform scalar loads; no LDS.  valid accumulated via atomicOr.
__global__ __launch_bounds__(256) void costmat_kernel(
    const float* __restrict__ paux,
    const float* __restrict__ clst,
    const float* __restrict__ gtaux,
    float* __restrict__ cost,
    float* __restrict__ iouM,
    int* __restrict__ validArr) {
#pragma clang fp contract(off)
  const int pblk = blockIdx.x, gch = blockIdx.y, b = blockIdx.z;
  const int p = pblk * 256 + threadIdx.x;
  if (p >= NP) return;
  const size_t idx = (size_t)b * NP + p;
  const float4* pa = (const float4*)(paux + idx * 16);
  float4 A = pa[0], Bq = pa[1], Cq = pa[2], Dq = pa[3];
  int vloc = 0;
  const int g0 = gch * GCH;
  for (int gl = 0; gl < GCH; ++gl) {
    const int g = g0 + gl;
    GTp t = load_gt(gtaux, b, g);
    float cls = clst[(size_t)t.label * NBPs + idx];
    float iou;
    int v;
    float cc = cost_base(A.x, A.y, A.z, A.w, Bq.x, Bq.y, Bq.z, Bq.w,
                         Cq.x, Cq.y, Cq.z, Cq.w, Dq.x, Dq.y, Dq.z,
                         cls, t, &iou, &v);
    const size_t ci = ((size_t)(b * NG + g)) * NP + p;
    cost[ci] = cc;
    iouM[ci] = iou;
    vloc |= v;
  }
  if (vloc) atomicOr(&validArr[idx], 1);
}

// ---------------------------------------------------------------------------
// Per-column selection.  Phase 1: 5 extraction rounds (desc) over iou fkeys ->
// dyn.  Phase 2: dyn extraction rounds (asc) over (cost+pen) fkeys.  Lastkey
// filter (keys unique) == stable rank order; no runtime-indexed reg writes.
__global__ __launch_bounds__(256) void select_kernel(
    const float* __restrict__ cost,
    const float* __restrict__ iouM,
    const int* __restrict__ validArr,
    const int* __restrict__ gtaux_unused,
    const int* __restrict__ head_ptr,
    int* __restrict__ colsel,
    int* __restrict__ rowcnt,
    int* __restrict__ rowassign) {
#pragma clang fp contract(off)
  const int g = blockIdx.x, b = blockIdx.y, tid = threadIdx.x;
  const int lane = tid & 63, wid = tid >> 6;
  const size_t cbase = ((size_t)(b * NG + g)) * NP;
  const size_t rowbase = (size_t)b * NP;
  __shared__ u64 sred[4];

  // ---- phase 1: iou top-5 values -> dyn
  uint32_t ki[VCHUNK][4];
#pragma unroll
  for (int i = 0; i < VCHUNK; ++i) {
    const int pb = i * 1024 + tid * 4;
    if (pb + 3 < NP) {
      float4 v = *(const float4*)(iouM + cbase + pb);
      ki[i][0] = fkey(v.x); ki[i][1] = fkey(v.y);
      ki[i][2] = fkey(v.z); ki[i][3] = fkey(v.w);
    } else {
#pragma unroll
      for (int j = 0; j < 4; ++j) {
        int p = pb + j;
        ki[i][j] = (p < NP) ? fkey(iouM[cbase + p]) : fkey(-INFINITY);
      }
    }
  }
  u64 last = 0;
  float sum5 = 0.0f;
  for (int k = 0; k < 5; ++k) {
    u64 best = 0;
#pragma unroll
    for (int i = 0; i < VCHUNK; ++i) {
#pragma unroll
      for (int j = 0; j < 4; ++j) {
        u64 key = ((u64)ki[i][j] << 32) | (unsigned)(i * 1024 + tid * 4 + j);
        if ((k == 0 || key < last) && key > best) best = key;
      }
    }
    u64 rr = block_max_u64(best, sred, lane, wid);
    float v = fkey_inv((uint32_t)(rr >> 32));
    sum5 = k ? (sum5 + v) : v;      // descending-order left-assoc sum
    last = rr;
  }
  const float adj = sum5 - 0.5f * (float)(6 - head_ptr[0]);
  int dyn = (int)adj;               // trunc toward zero == astype(int32)
  if (dyn < 1) dyn = 1;
  if (dyn > SELMAX) dyn = SELMAX;

  // ---- phase 2: dyn smallest (cost+pen, p)
  uint32_t kc[VCHUNK][4];
#pragma unroll
  for (int i = 0; i < VCHUNK; ++i) {
    const int pb = i * 1024 + tid * 4;
    if (pb + 3 < NP) {
      float4 c = *(const float4*)(cost + cbase + pb);
      int4 vv = *(const int4*)(validArr + rowbase + pb);
      kc[i][0] = fkey(c.x + (vv.x ? 0.0f : 10000.0f));
      kc[i][1] = fkey(c.y + (vv.y ? 0.0f : 10000.0f));
      kc[i][2] = fkey(c.z + (vv.z ? 0.0f : 10000.0f));
      kc[i][3] = fkey(c.w + (vv.w ? 0.0f : 10000.0f));
    } else {
#pragma unroll
      for (int j = 0; j < 4; ++j) {
        int p = pb + j;
        kc[i][j] = (p < NP)
            ? fkey(cost[cbase + p] + (validArr[rowbase + p] ? 0.0f : 10000.0f))
            : fkey(INFINITY);
      }
    }
  }
  const size_t cb = ((size_t)(b * NG + g)) * SELMAX;
  last = 0;
  for (int k = 0; k < dyn; ++k) {
    u64 best = ~0ull;
#pragma unroll
    for (int i = 0; i < VCHUNK; ++i) {
#pragma unroll
      for (int j = 0; j < 4; ++j) {
        u64 key = ((u64)kc[i][j] << 32) | (unsigned)(i * 1024 + tid * 4 + j);
        if ((k == 0 || key > last) && key < best) best = key;
      }
    }
    u64 rr = block_min_u64(best, sred, lane, wid);
    if (tid == 0) {
      int pw = (int)(rr & 0xffffffffu);
      colsel[cb + k] = pw;
      atomicAdd(&rowcnt[rowbase + pw], 1);
      atomicMin(&rowassign[rowbase + pw], g);
    }
    last = rr;
  }
  if (tid == 0) {
    for (int k = dyn; k < SELMAX; ++k) colsel[cb + k] = -1;
  }
}

// Column counts part (a): selections on rows that stayed single (rowcnt==1).
__global__ void colcnt_a_kernel(const int* __restrict__ colsel,
                                const int* __restrict__ rowcnt,
                                int* __restrict__ colcnt) {
  int i = blockIdx.x * 256 + threadIdx.x;
  if (i >= NB * NG) return;
  int b = i / NG;
  int cnt = 0;
  for (int k = 0; k < SELMAX; ++k) {
    int s = colsel[(size_t)i * SELMAX + k];
    if (s >= 0 && rowcnt[(size_t)b * NP + s] == 1) cnt++;
  }
  colcnt[i] = cnt;
}

// Prior rows (rowcnt>1): row argmin over g from the cost matrix (+pen, as the
// reference does), scatter into colcnt (part b).  Rare rows.
__global__ __launch_bounds__(256) void rowmin_prior_kernel(
    const float* __restrict__ cost,
    const int* __restrict__ validArr,
    const int* __restrict__ rowcnt,
    int* __restrict__ rowminArr,
    int* __restrict__ colcnt) {
#pragma clang fp contract(off)
  const int b = blockIdx.y, p = blockIdx.x * 256 + threadIdx.x;
  if (p >= NP) return;
  const size_t idx = (size_t)b * NP + p;
  if (rowcnt[idx] <= 1) return;
  const float pen = validArr[idx] ? 0.0f : 10000.0f;
  float best = INFINITY;
  int bg = 0;
#pragma unroll 8
  for (int g = 0; g < NG; ++g) {
    float v = cost[((size_t)(b * NG + g)) * NP + p] + pen;
    if (v < best) { best = v; bg = g; }   // strict <: first-g tiebreak
  }
  rowminArr[idx] = bg;
  atomicAdd(&colcnt[b * NG + bg], 1);
}

// Empty columns: argmin over never-matched rows of (cost+pen, p).
__global__ __launch_bounds__(256) void fixup_kernel(
    const float* __restrict__ cost,
    const int* __restrict__ validArr,
    const int* __restrict__ colcnt,
    const int* __restrict__ rowcnt,
    int* __restrict__ rowassign) {
#pragma clang fp contract(off)
  const int g = blockIdx.x, b = blockIdx.y, tid = threadIdx.x;
  if (colcnt[b * NG + g] != 0) return;  // uniform across block
  const int lane = tid & 63, wid = tid >> 6;
  const size_t cbase = ((size_t)(b * NG + g)) * NP;
  const size_t rowbase = (size_t)b * NP;
  __shared__ u64 sred[4];
  u64 best = ~0ull;
  for (int p = tid; p < NP; p += 256) {
    if (rowcnt[rowbase + p] == 0) {
      float c = cost[cbase + p] + (validArr[rowbase + p] ? 0.0f : 10000.0f);
      u64 key = ((u64)fkey(c) << 32) | (unsigned)p;
      if (key < best) best = key;
    }
  }
  u64 rr = block_min_u64(best, sred, lane, wid);
  if (tid == 0) {
    int pos = (int)(rr & 0xffffffffu);
    atomicMin(&rowassign[rowbase + pos], g);  // min g == argmax first-1
  }
}

__global__ void output_kernel(const int* __restrict__ rowcnt,
                              const int* __restrict__ rowassign,
                              const int* __restrict__ rowminArr,
                              int* __restrict__ out) {
  int b = blockIdx.y, p = blockIdx.x * 256 + threadIdx.x;
  if (p >= NP) return;
  size_t idx = (size_t)b * NP + p;
  int rc = rowcnt[idx];
  int fg, m;
  if (rc == 0) {
    int ra = rowassign[idx];
    if (ra == 0x7fffffff) { fg = 0; m = -1; }
    else { fg = 1; m = ra; }          // fixup-assigned (min g)
  } else if (rc == 1) {
    fg = 1; m = rowassign[idx];       // single selecting column
  } else {
    fg = 1; m = rowminArr[idx];       // prior row -> one-hot at row argmin
  }
  out[idx] = fg;
  out[(size_t)NB * NP + idx] = m;
}

// ---------------------------------------------------------------------------
extern "C" void kernel_launch(void* const* d_in, const int* in_sizes, int n_in,
                              void* d_out, int out_size, void* d_ws, size_t ws_size,
                              hipStream_t stream) {
  const float* pred_logits = (const float*)d_in[0];
  const float* pred_boxes = (const float*)d_in[1];
  const float* gt_boxes = (const float*)d_in[2];
  const int* gt_labels = (const int*)d_in[3];
  const int* head = (const int*)d_in[4];
  (void)in_sizes; (void)n_in; (void)out_size; (void)ws_size;

  char* w = (char*)d_ws;
  size_t off = 0;
  auto alloc = [&](size_t bytes) -> void* {
    void* p = w + off;
    off += (bytes + 255) & ~(size_t)255;
    return p;
  };
  float* cost = (float*)alloc((size_t)NB * NG * NP * 4);   // 49.2 MB
  float* iouM = (float*)alloc((size_t)NB * NG * NP * 4);   // 49.2 MB
  float* paux = (float*)alloc((size_t)NB * NP * 16 * 4);   // 6.1 MB
  float* clst = (float*)alloc((size_t)NC * NB * NP * 4);   // 3.8 MB
  float* gtaux = (float*)alloc((size_t)NB * NG * GSTR * 4);
  int* validArr = (int*)alloc((size_t)NB * NP * 4);
  int* colsel = (int*)alloc((size_t)NB * NG * SELMAX * 4);
  int* rowcnt = (int*)alloc((size_t)NB * NP * 4);
  int* rowassign = (int*)alloc((size_t)NB * NP * 4);
  int* rowminArr = (int*)alloc((size_t)NB * NP * 4);
  int* colcnt = (int*)alloc((size_t)NB * NG * 4);

  int* out = (int*)d_out;
  dim3 blk(256);
  prep_gt_kernel<<<dim3(NB), dim3(128), 0, stream>>>(gt_boxes, gt_labels, gtaux);
  prep_pred_kernel<<<dim3((NP + 255) / 256, NB), blk, 0, stream>>>(
      pred_logits, pred_boxes, paux, clst, validArr, rowcnt, rowassign);
  costmat_kernel<<<dim3((NP + 255) / 256, NG / GCH, NB), blk, 0, stream>>>(
      paux, clst, gtaux, cost, iouM, validArr);
  select_kernel<<<dim3(NG, NB), blk, 0, stream>>>(
      cost, iouM, validArr, nullptr, head, colsel, rowcnt, rowassign);
  colcnt_a_kernel<<<dim3((NB * NG + 255) / 256), blk, 0, stream>>>(colsel, rowcnt, colcnt);
  rowmin_prior_kernel<<<dim3((NP + 255) / 256, NB), blk, 0, stream>>>(
      cost, validArr, rowcnt, rowminArr, colcnt);
  fixup_kernel<<<dim3(NG, NB), blk, 0, stream>>>(
      cost, validArr, colcnt, rowcnt, rowassign);
  output_kernel<<<dim3((NP + 255) / 256, NB), blk, 0, stream>>>(
      rowcnt, rowassign, rowminArr, out);
}